// Round 1
// baseline (411.626 us; speedup 1.0000x reference)
//
#include <hip/hip_runtime.h>
#include <cstdint>
#include <math.h>

#define H 1024
#define V 50257

// ---- monotone float<->uint encoding for atomicMax on floats ----
__device__ __forceinline__ unsigned fenc(float f) {
    unsigned b = __float_as_uint(f);
    return (b & 0x80000000u) ? ~b : (b | 0x80000000u);
}
__device__ __forceinline__ float fdec(unsigned k) {
    unsigned b = (k & 0x80000000u) ? (k ^ 0x80000000u) : ~k;
    return __uint_as_float(b);
}

__device__ __forceinline__ float dot4(float4 a, float4 b) {
    return a.x * b.x + a.y * b.y + a.z * b.z + a.w * b.w;
}

// One block (256 thr) per output element i: 6 dot products of length H
// (W_ih rows i, H+i, 2H+i and W_hh rows i, H+i, 2H+i), then the GRU gates.
__global__ __launch_bounds__(256) void gru_layer(
    const float* __restrict__ emb, const int* __restrict__ tok, int use_emb,
    const float* __restrict__ xvec,
    const float* __restrict__ hprev,
    const float* __restrict__ Wih, const float* __restrict__ Whh,
    const float* __restrict__ bih, const float* __restrict__ bhh,
    float* __restrict__ hnew_ws, float* __restrict__ hnew_out,
    unsigned* __restrict__ maxkey, float* __restrict__ sumacc, int do_init)
{
    const int i = blockIdx.x;    // 0..H-1
    const int t = threadIdx.x;   // 0..255  (thread t covers elems 4t..4t+3)
    if (do_init && i == 0 && t == 0) { *maxkey = 0u; *sumacc = 0.0f; }

    const float* xb = use_emb ? (emb + (size_t)tok[0] * (size_t)H) : xvec;
    float4 xv = *(const float4*)(xb + 4 * t);
    if (use_emb) {
        xv.x = fmaxf(xv.x, 0.f); xv.y = fmaxf(xv.y, 0.f);
        xv.z = fmaxf(xv.z, 0.f); xv.w = fmaxf(xv.w, 0.f);
    }

    float s[6];
    {
        const float* r0 = Wih + (size_t)i * H;
        const float* r1 = Wih + (size_t)(H + i) * H;
        const float* r2 = Wih + (size_t)(2 * H + i) * H;
        const float* r3 = Whh + (size_t)i * H;
        const float* r4 = Whh + (size_t)(H + i) * H;
        const float* r5 = Whh + (size_t)(2 * H + i) * H;
        s[0] = dot4(*(const float4*)(r0 + 4 * t), xv);
        s[1] = dot4(*(const float4*)(r1 + 4 * t), xv);
        s[2] = dot4(*(const float4*)(r2 + 4 * t), xv);
        float4 hv = *(const float4*)(hprev + 4 * t);
        s[3] = dot4(*(const float4*)(r3 + 4 * t), hv);
        s[4] = dot4(*(const float4*)(r4 + 4 * t), hv);
        s[5] = dot4(*(const float4*)(r5 + 4 * t), hv);
    }

    #pragma unroll
    for (int m = 1; m < 64; m <<= 1) {
        #pragma unroll
        for (int k = 0; k < 6; ++k) s[k] += __shfl_xor(s[k], m);
    }
    __shared__ float red[4][6];
    const int wv = t >> 6, ln = t & 63;
    if (ln == 0) {
        #pragma unroll
        for (int k = 0; k < 6; ++k) red[wv][k] = s[k];
    }
    __syncthreads();
    if (t == 0) {
        float g[6];
        #pragma unroll
        for (int k = 0; k < 6; ++k)
            g[k] = red[0][k] + red[1][k] + red[2][k] + red[3][k];
        float gir = g[0] + bih[i], giz = g[1] + bih[H + i], gin = g[2] + bih[2 * H + i];
        float ghr = g[3] + bhh[i], ghz = g[4] + bhh[H + i], ghn = g[5] + bhh[2 * H + i];
        float r = 1.f / (1.f + expf(-(gir + ghr)));
        float z = 1.f / (1.f + expf(-(giz + ghz)));
        float n = tanhf(gin + r * ghn);
        float hp = hprev[i];
        float hn = (1.f - z) * n + z * hp;
        hnew_ws[i] = hn;
        hnew_out[i] = hn;
    }
}

// Wave-per-row matvec over W_out (V x H). Writes raw logits into d_out[0..V),
// tracks per-block max -> atomicMax(maxkey).
__global__ __launch_bounds__(256) void proj_kernel(
    const float* __restrict__ h, const float* __restrict__ Wout,
    const float* __restrict__ bout, float* __restrict__ logits,
    unsigned* __restrict__ maxkey)
{
    const int t = threadIdx.x;
    const int wv = t >> 6, ln = t & 63;
    const int gw = blockIdx.x * 4 + wv;
    const int nw = gridDim.x * 4;

    float4 hr[4];
    #pragma unroll
    for (int j = 0; j < 4; ++j) hr[j] = *(const float4*)(h + 4 * (ln + 64 * j));

    float wmax = -INFINITY;
    for (int v = gw; v < V; v += nw) {
        const float* wrow = Wout + (size_t)v * H;
        float s = 0.f;
        #pragma unroll
        for (int j = 0; j < 4; ++j)
            s += dot4(*(const float4*)(wrow + 4 * (ln + 64 * j)), hr[j]);
        #pragma unroll
        for (int m = 1; m < 64; m <<= 1) s += __shfl_xor(s, m);
        s += bout[v];                 // all lanes have the full sum
        if (ln == 0) logits[v] = s;
        wmax = fmaxf(wmax, s);
    }
    __shared__ float smax[4];
    if (ln == 0) smax[wv] = wmax;
    __syncthreads();
    if (t == 0) {
        float m = fmaxf(fmaxf(smax[0], smax[1]), fmaxf(smax[2], smax[3]));
        atomicMax(maxkey, fenc(m));
    }
}

__global__ __launch_bounds__(256) void sumexp_kernel(
    const float* __restrict__ logits, const unsigned* __restrict__ maxkey,
    float* __restrict__ sumacc)
{
    const float m = fdec(*maxkey);
    float loc = 0.f;
    for (int v = blockIdx.x * 256 + threadIdx.x; v < V; v += gridDim.x * 256)
        loc += expf(logits[v] - m);
    #pragma unroll
    for (int s = 1; s < 64; s <<= 1) loc += __shfl_xor(loc, s);
    __shared__ float sl[4];
    if ((threadIdx.x & 63) == 0) sl[threadIdx.x >> 6] = loc;
    __syncthreads();
    if (threadIdx.x == 0) atomicAdd(sumacc, sl[0] + sl[1] + sl[2] + sl[3]);
}

__global__ __launch_bounds__(256) void finalize_kernel(
    float* __restrict__ logits, const unsigned* __restrict__ maxkey,
    const float* __restrict__ sumacc)
{
    const float m = fdec(*maxkey);
    const float lz = logf(*sumacc);
    for (int v = blockIdx.x * 256 + threadIdx.x; v < V; v += gridDim.x * 256)
        logits[v] = logits[v] - m - lz;
}

extern "C" void kernel_launch(void* const* d_in, const int* in_sizes, int n_in,
                              void* d_out, int out_size, void* d_ws, size_t ws_size,
                              hipStream_t stream) {
    const int*   tok    = (const int*)d_in[0];     // low 32 bits of int64 ok (LE)
    const float* hidden = (const float*)d_in[1];   // (2,1,H)
    const float* emb    = (const float*)d_in[2];   // (V,H)
    const float* Wih    = (const float*)d_in[3];   // (2,3H,H)
    const float* Whh    = (const float*)d_in[4];
    const float* bih    = (const float*)d_in[5];   // (2,3H)
    const float* bhh    = (const float*)d_in[6];
    const float* Wout   = (const float*)d_in[7];   // (V,H)
    const float* bout   = (const float*)d_in[8];   // (V,)

    float* out = (float*)d_out;        // [0,V): logprobs; [V,V+2H): hidden_new
    float* ws  = (float*)d_ws;
    unsigned* maxkey = (unsigned*)ws;  // ws[0]
    float* sumacc = ws + 1;            // ws[1]
    float* h0 = ws + 8;                // ws[8 .. 8+H)
    float* h1 = ws + 8 + H;            // ws[8+H .. 8+2H)

    // layer 0 (x = relu(emb[tok]) computed inline); also inits accumulators
    gru_layer<<<H, 256, 0, stream>>>(emb, tok, 1, nullptr, hidden,
                                     Wih, Whh, bih, bhh,
                                     h0, out + V, maxkey, sumacc, 1);
    // layer 1
    gru_layer<<<H, 256, 0, stream>>>(nullptr, nullptr, 0, h0, hidden + H,
                                     Wih + 3 * H * H, Whh + 3 * H * H,
                                     bih + 3 * H, bhh + 3 * H,
                                     h1, out + V + H, maxkey, sumacc, 0);
    // output projection (logits into d_out in place) + global max
    proj_kernel<<<1024, 256, 0, stream>>>(h1, Wout, bout, out, maxkey);
    // sum of exp(logit - max)
    sumexp_kernel<<<128, 256, 0, stream>>>(out, maxkey, sumacc);
    // logprob = logit - max - log(sum), in place
    finalize_kernel<<<128, 256, 0, stream>>>(out, maxkey, sumacc);
}

// Round 2
// 411.467 us; speedup vs baseline: 1.0004x; 1.0004x over previous
//
#include <hip/hip_runtime.h>
#include <cstdint>
#include <math.h>

#define H 1024
#define V 50257
#define PBLK 2048   // proj grid; also number of logsumexp partials

__device__ __forceinline__ float dot4(float4 a, float4 b) {
    return a.x * b.x + a.y * b.y + a.z * b.z + a.w * b.w;
}

// One block (256 thr) per output element i: 6 dot products of length H
// (W_ih rows i, H+i, 2H+i and W_hh rows i, H+i, 2H+i), then the GRU gates.
__global__ __launch_bounds__(256) void gru_layer(
    const float* __restrict__ emb, const int* __restrict__ tok, int use_emb,
    const float* __restrict__ xvec,
    const float* __restrict__ hprev,
    const float* __restrict__ Wih, const float* __restrict__ Whh,
    const float* __restrict__ bih, const float* __restrict__ bhh,
    float* __restrict__ hnew_ws, float* __restrict__ hnew_out)
{
    const int i = blockIdx.x;    // 0..H-1
    const int t = threadIdx.x;   // 0..255  (thread t covers elems 4t..4t+3)

    const float* xb = use_emb ? (emb + (size_t)tok[0] * (size_t)H) : xvec;
    float4 xv = *(const float4*)(xb + 4 * t);
    if (use_emb) {
        xv.x = fmaxf(xv.x, 0.f); xv.y = fmaxf(xv.y, 0.f);
        xv.z = fmaxf(xv.z, 0.f); xv.w = fmaxf(xv.w, 0.f);
    }

    float s[6];
    {
        const float* r0 = Wih + (size_t)i * H;
        const float* r1 = Wih + (size_t)(H + i) * H;
        const float* r2 = Wih + (size_t)(2 * H + i) * H;
        const float* r3 = Whh + (size_t)i * H;
        const float* r4 = Whh + (size_t)(H + i) * H;
        const float* r5 = Whh + (size_t)(2 * H + i) * H;
        s[0] = dot4(*(const float4*)(r0 + 4 * t), xv);
        s[1] = dot4(*(const float4*)(r1 + 4 * t), xv);
        s[2] = dot4(*(const float4*)(r2 + 4 * t), xv);
        float4 hv = *(const float4*)(hprev + 4 * t);
        s[3] = dot4(*(const float4*)(r3 + 4 * t), hv);
        s[4] = dot4(*(const float4*)(r4 + 4 * t), hv);
        s[5] = dot4(*(const float4*)(r5 + 4 * t), hv);
    }

    #pragma unroll
    for (int m = 1; m < 64; m <<= 1) {
        #pragma unroll
        for (int k = 0; k < 6; ++k) s[k] += __shfl_xor(s[k], m);
    }
    __shared__ float red[4][6];
    const int wv = t >> 6, ln = t & 63;
    if (ln == 0) {
        #pragma unroll
        for (int k = 0; k < 6; ++k) red[wv][k] = s[k];
    }
    __syncthreads();
    if (t == 0) {
        float g[6];
        #pragma unroll
        for (int k = 0; k < 6; ++k)
            g[k] = red[0][k] + red[1][k] + red[2][k] + red[3][k];
        float gir = g[0] + bih[i], giz = g[1] + bih[H + i], gin = g[2] + bih[2 * H + i];
        float ghr = g[3] + bhh[i], ghz = g[4] + bhh[H + i], ghn = g[5] + bhh[2 * H + i];
        float r = 1.f / (1.f + expf(-(gir + ghr)));
        float z = 1.f / (1.f + expf(-(giz + ghz)));
        float n = tanhf(gin + r * ghn);
        float hp = hprev[i];
        float hn = (1.f - z) * n + z * hp;
        hnew_ws[i] = hn;
        hnew_out[i] = hn;
    }
}

// Wave-per-row matvec over W_out (V x H). Writes raw logits into d_out[0..V),
// and a per-block online-logsumexp partial (pmax, psum) into ws.
__global__ __launch_bounds__(256) void proj_kernel(
    const float* __restrict__ h, const float* __restrict__ Wout,
    const float* __restrict__ bout, float* __restrict__ logits,
    float* __restrict__ pmax, float* __restrict__ psum)
{
    const int t = threadIdx.x;
    const int wv = t >> 6, ln = t & 63;
    const int gw = blockIdx.x * 4 + wv;
    const int nw = PBLK * 4;

    float4 hr[4];
    #pragma unroll
    for (int j = 0; j < 4; ++j) hr[j] = *(const float4*)(h + 4 * (ln + 64 * j));

    float wmax = -INFINITY, wsum = 0.f;
    for (int v = gw; v < V; v += nw) {
        const float* wrow = Wout + (size_t)v * H;
        float s = 0.f;
        #pragma unroll
        for (int j = 0; j < 4; ++j)
            s += dot4(*(const float4*)(wrow + 4 * (ln + 64 * j)), hr[j]);
        #pragma unroll
        for (int m = 1; m < 64; m <<= 1) s += __shfl_xor(s, m);
        s += bout[v];                 // all lanes now hold the full row sum
        if (ln == 0) logits[v] = s;
        float nm = fmaxf(wmax, s);    // online logsumexp (uniform across wave)
        wsum = wsum * expf(wmax - nm) + expf(s - nm);
        wmax = nm;
    }
    __shared__ float smax[4], ssum[4];
    if (ln == 0) { smax[wv] = wmax; ssum[wv] = wsum; }
    __syncthreads();
    if (t == 0) {
        float m = fmaxf(fmaxf(smax[0], smax[1]), fmaxf(smax[2], smax[3]));
        float su = 0.f;
        #pragma unroll
        for (int w = 0; w < 4; ++w) su += ssum[w] * expf(smax[w] - m);
        pmax[blockIdx.x] = m;
        psum[blockIdx.x] = su;
    }
}

// Each block redundantly reduces the PBLK (L2-resident) partials to logZ,
// then subtracts over its slice of the logits (in place).
__global__ __launch_bounds__(256) void finalize_kernel(
    float* __restrict__ logits,
    const float* __restrict__ pmax, const float* __restrict__ psum)
{
    const int t = threadIdx.x;
    float m = -INFINITY, su = 0.f;
    for (int i = t; i < PBLK; i += 256) {
        float om = pmax[i], os = psum[i];
        float nm = fmaxf(m, om);
        su = su * expf(m - nm) + os * expf(om - nm);
        m = nm;
    }
    #pragma unroll
    for (int k = 1; k < 64; k <<= 1) {
        float om = __shfl_xor(m, k), os = __shfl_xor(su, k);
        float nm = fmaxf(m, om);
        su = su * expf(m - nm) + os * expf(om - nm);
        m = nm;
    }
    __shared__ float smax[4], ssum[4], slz;
    if ((t & 63) == 0) { smax[t >> 6] = m; ssum[t >> 6] = su; }
    __syncthreads();
    if (t == 0) {
        float mm = fmaxf(fmaxf(smax[0], smax[1]), fmaxf(smax[2], smax[3]));
        float ss = 0.f;
        #pragma unroll
        for (int w = 0; w < 4; ++w) ss += ssum[w] * expf(smax[w] - mm);
        slz = mm + logf(ss);
    }
    __syncthreads();
    const float lz = slz;
    for (int v = blockIdx.x * 256 + t; v < V; v += gridDim.x * 256)
        logits[v] = logits[v] - lz;
}

extern "C" void kernel_launch(void* const* d_in, const int* in_sizes, int n_in,
                              void* d_out, int out_size, void* d_ws, size_t ws_size,
                              hipStream_t stream) {
    const int*   tok    = (const int*)d_in[0];     // low 32 bits of int64 ok (LE)
    const float* hidden = (const float*)d_in[1];   // (2,1,H)
    const float* emb    = (const float*)d_in[2];   // (V,H)
    const float* Wih    = (const float*)d_in[3];   // (2,3H,H)
    const float* Whh    = (const float*)d_in[4];
    const float* bih    = (const float*)d_in[5];   // (2,3H)
    const float* bhh    = (const float*)d_in[6];
    const float* Wout   = (const float*)d_in[7];   // (V,H)
    const float* bout   = (const float*)d_in[8];   // (V,)

    float* out = (float*)d_out;        // [0,V): logprobs; [V,V+2H): hidden_new
    float* ws  = (float*)d_ws;
    float* pmax = ws;                  // [0, PBLK)
    float* psum = ws + PBLK;           // [PBLK, 2*PBLK)
    float* h0 = ws + 2 * PBLK;         // H floats
    float* h1 = ws + 2 * PBLK + H;     // H floats

    // layer 0 (x = relu(emb[tok]) computed inline)
    gru_layer<<<H, 256, 0, stream>>>(emb, tok, 1, nullptr, hidden,
                                     Wih, Whh, bih, bhh, h0, out + V);
    // layer 1
    gru_layer<<<H, 256, 0, stream>>>(nullptr, nullptr, 0, h0, hidden + H,
                                     Wih + 3 * H * H, Whh + 3 * H * H,
                                     bih + 3 * H, bhh + 3 * H, h1, out + V + H);
    // output projection (logits into d_out in place) + per-block lse partials
    proj_kernel<<<PBLK, 256, 0, stream>>>(h1, Wout, bout, out, pmax, psum);
    // reduce partials (redundant per block) and subtract logZ in place
    finalize_kernel<<<256, 256, 0, stream>>>(out, pmax, psum);
}